// Round 6
// baseline (78.855 us; speedup 1.0000x reference)
//
#include <hip/hip_runtime.h>

// FUME epipolar translation, fp32 in/out. B from in_sizes[3]; C,H,W = 4,128,128.
//
// R6: one load per step. Staged entry ws[k][u] packs BOTH bilinear taps for
// all 4 channels in fp16: { half2(v[ch][u], v[ch][u+1]) : ch=0..3 } = 16 B.
// Inner loop: 1 aligned dwordx4 + 4 x v_dot2_f32_f16 (acc += omw*v0 + wz*v1)
// per step, replacing R5's 2 loads + 8 fmas. u/mask math is bit-identical to
// R5 (fp32, reference op order, one reciprocal) so mask decisions don't move;
// fp16 tap/weight rounding adds ~1e-2 RMS (threshold 0.309).
//
// Workspace (16B entries): per batch b, 2 cubes of 128x128 entries:
//   horiz cube at entry ofs b*32768:        row r=x, col u=y : taps img[ch][u][x], img[ch][u+1][x]
//   vert  cube at entry ofs b*32768+16384:  row r=y, col u=x : taps img[ch][r][u], img[ch][r][u+1]
// (u+1 clamped to 127 at the edge; entry col 127 is never read since i0<=126.)

#define CC 4
#define HH 128
#define WW 128

typedef _Float16 h2 __attribute__((ext_vector_type(2)));

__global__ void fume_stage(const float* __restrict__ img, float4* __restrict__ ws) {
    __shared__ float tile[4][33][33];   // [ch][row-ty0][col-tx0], 33x33 halo
    int tx0 = blockIdx.x * 32, ty0 = blockIdx.y * 32, b = blockIdx.z;
    int tx = threadIdx.x, ty = threadIdx.y;
    const float* src = img + (size_t)b * CC * HH * WW;
    int c32 = min(tx0 + 32, WW - 1);
    #pragma unroll
    for (int ch = 0; ch < 4; ++ch) {
        for (int i = ty; i < 33; i += 8) {
            int r = min(ty0 + i, HH - 1);
            tile[ch][i][tx] = src[(ch * HH + r) * WW + tx0 + tx];
            if (tx == 0) tile[ch][i][32] = src[(ch * HH + r) * WW + c32];
        }
    }
    __syncthreads();

    float4* base_h = ws + (size_t)b * 32768;
    float4* base_v = base_h + 16384;
    #pragma unroll
    for (int i = ty; i < 32; i += 8) {
        // vert entry: k = ty0+i, u = tx0+tx : taps tile[ch][i][tx], tile[ch][i][tx+1]
        {
            h2 p0 = { (_Float16)tile[0][i][tx], (_Float16)tile[0][i][tx + 1] };
            h2 p1 = { (_Float16)tile[1][i][tx], (_Float16)tile[1][i][tx + 1] };
            h2 p2 = { (_Float16)tile[2][i][tx], (_Float16)tile[2][i][tx + 1] };
            h2 p3 = { (_Float16)tile[3][i][tx], (_Float16)tile[3][i][tx + 1] };
            float4 e = make_float4(__builtin_bit_cast(float, p0),
                                   __builtin_bit_cast(float, p1),
                                   __builtin_bit_cast(float, p2),
                                   __builtin_bit_cast(float, p3));
            base_v[(ty0 + i) * WW + (tx0 + tx)] = e;
        }
        // horiz entry: r = x = tx0+i, u = y = ty0+tx : taps tile[ch][tx][i], tile[ch][tx+1][i]
        {
            h2 p0 = { (_Float16)tile[0][tx][i], (_Float16)tile[0][tx + 1][i] };
            h2 p1 = { (_Float16)tile[1][tx][i], (_Float16)tile[1][tx + 1][i] };
            h2 p2 = { (_Float16)tile[2][tx][i], (_Float16)tile[2][tx + 1][i] };
            h2 p3 = { (_Float16)tile[3][tx][i], (_Float16)tile[3][tx + 1][i] };
            float4 e = make_float4(__builtin_bit_cast(float, p0),
                                   __builtin_bit_cast(float, p1),
                                   __builtin_bit_cast(float, p2),
                                   __builtin_bit_cast(float, p3));
            base_h[(tx0 + i) * HH + (ty0 + tx)] = e;
        }
    }
}

__global__ void __launch_bounds__(512) fume_kernel(
        const float4* __restrict__ cubes,
        const float* __restrict__ F,
        const float* __restrict__ dsf,
        float* __restrict__ out) {
    int tx  = threadIdx.x;               // 0..63 : x within group (one wave)
    int seg = threadIdx.y;               // 0..7  : k-segment (wave id)
    int x = blockIdx.x * 64 + tx;
    int y = blockIdx.y;
    int b = blockIdx.z;

    float d = dsf[b];
    float F00 = F[0], F01 = F[1], F02 = F[2];
    float F10 = F[3], F11 = F[4], F12 = F[5];
    float F20 = F[6], F21 = F[7], F22 = F[8];

    // Exact reference op order (no fma contraction).
    float px = __fmul_rn((float)x, d);
    float py = __fmul_rn((float)y, d);
    float av = __fadd_rn(__fadd_rn(__fmul_rn(F00, px), __fmul_rn(F01, py)), F02);
    float bv = __fadd_rn(__fadd_rn(__fmul_rn(F10, px), __fmul_rn(F11, py)), F12);
    float cv = __fadd_rn(__fadd_rn(__fmul_rn(F20, px), __fmul_rn(F21, py)), F22);

    bool horiz  = fabsf(bv) >= fabsf(av);
    float ncoef = horiz ? av : bv;
    float den   = __fmul_rn(horiz ? bv : av, d);
    float nrec  = -__fdiv_rn(1.0f, den);   // den 0/Inf/NaN -> u NaN -> masked

    const float4* P = cubes + (size_t)b * 32768 + (horiz ? 0 : 16384);

    // Conservative valid-k interval (exact per-step mask still applied).
    float A  = __fmul_rn(__fmul_rn(ncoef, d), nrec);
    float Bc = __fmul_rn(cv, nrec);
    int lkmin, lkmax;
    if (fabsf(A) > 1e-20f) {
        float inv = 1.0f / A;
        float k1 = (0.0f   - Bc) * inv;
        float k2 = (127.0f - Bc) * inv;
        float lo = fmaxf(fminf(k1, k2) - 2.0f, 0.0f);
        float hi = fminf(fmaxf(k1, k2) + 2.0f, 127.0f);
        if (lo > hi || !(lo == lo)) { lkmin = 1; lkmax = 0; }
        else { lkmin = (int)lo; lkmax = (int)hi; }
    } else {
        bool full = (Bc >= 0.0f) && (Bc <= 127.0f);
        lkmin = full ? 0 : 1;
        lkmax = full ? 127 : 0;
    }
    int wkmin = lkmin, wkmax = lkmax;
    #pragma unroll
    for (int off = 1; off < 64; off <<= 1) {
        wkmin = min(wkmin, __shfl_xor(wkmin, off));
        wkmax = max(wkmax, __shfl_xor(wkmax, off));
    }

    float a0 = 0.f, a1 = 0.f, a2 = 0.f, a3 = 0.f;
    int len = wkmax - wkmin + 1;
    if (len > 0) {
        int cnt = (len + 7) >> 3;
        int ks  = wkmin + seg * cnt;
        int ke  = min(ks + cnt - 1, wkmax);
        #pragma unroll 4
        for (int k = ks; k <= ke; ++k) {
            float m  = __fmul_rn((float)k, d);
            float q  = __fadd_rn(__fmul_rn(ncoef, m), cv);
            float u  = __fmul_rn(q, nrec);
            bool ok  = (u >= 0.f) && (u <= 127.f);
            int i0   = (int)floorf(u);            // NaN->0, sat; clamped next
            i0 = max(0, min(i0, 126));
            float w  = __fsub_rn(u, (float)i0);   // ==1 at u==127 -> row[127]
            float wz  = ok ? w : 0.f;
            float omw = ok ? __fsub_rn(1.f, w) : 0.f;
            h2 wp = { (_Float16)omw, (_Float16)wz };
            float4 e = P[k * 128 + i0];
            a0 = __builtin_amdgcn_fdot2(wp, __builtin_bit_cast(h2, e.x), a0, false);
            a1 = __builtin_amdgcn_fdot2(wp, __builtin_bit_cast(h2, e.y), a1, false);
            a2 = __builtin_amdgcn_fdot2(wp, __builtin_bit_cast(h2, e.z), a2, false);
            a3 = __builtin_amdgcn_fdot2(wp, __builtin_bit_cast(h2, e.w), a3, false);
        }
    }

    __shared__ float part[8][4][64];
    part[seg][0][tx] = a0;
    part[seg][1][tx] = a1;
    part[seg][2][tx] = a2;
    part[seg][3][tx] = a3;
    __syncthreads();

    if (seg < 4) {                                // waves 0..3: one channel each
        int ch = seg;
        float s = part[0][ch][tx];
        #pragma unroll
        for (int t = 1; t < 8; ++t) s = __fadd_rn(s, part[t][ch][tx]);
        out[(((size_t)b * CC + ch) * HH + y) * WW + x] = s;
    }
}

extern "C" void kernel_launch(void* const* d_in, const int* in_sizes, int n_in,
                              void* d_out, int out_size, void* d_ws, size_t ws_size,
                              hipStream_t stream) {
    const float* view1 = (const float*)d_in[0];
    const float* F21   = (const float*)d_in[1];
    const float* dsf   = (const float*)d_in[3];

    const int B = in_sizes[3];

    dim3 stb(32, 8, 1);
    dim3 stg(WW / 32, HH / 32, B);
    fume_stage<<<stg, stb, 0, stream>>>(view1, (float4*)d_ws);

    dim3 ftb(64, 8, 1);
    dim3 ftg(WW / 64, HH, B);
    fume_kernel<<<ftg, ftb, 0, stream>>>((const float4*)d_ws, F21, dsf,
                                         (float*)d_out);
}

// Round 7
// 70.479 us; speedup vs baseline: 1.1188x; 1.1188x over previous
//
#include <hip/hip_runtime.h>

// FUME epipolar translation, fp32 in/out. B from in_sizes[3]; C,H,W = 4,128,128.
//
// R7: R6's fume kernel kept verbatim (1 dwordx4 + 4 v_dot2_f32_f16 per step;
// absmax 0.0156 vs threshold 0.309). Stage rewritten for parallelism: R6's
// stage ran 64 blocks (1 wave / 4 SIMDs, latency-exposed) with a heavy halo
// body. Now: 16x16 tiles -> 256 blocks / 1024 waves, LDS float[4][17][17],
// one vert + one horiz entry per thread (16 cvt + 2 stores).
//
// Workspace (16B entries = {half2(v[ch][u],v[ch][u+1])}ch=0..3):
//   horiz cube at entry ofs b*32768:        row r=x, col u=y : taps img[ch][u][x], img[ch][u+1][x]
//   vert  cube at entry ofs b*32768+16384:  row r=y, col u=x : taps img[ch][r][u], img[ch][r][u+1]
// (tap u+1 clamped at the image edge; entry col 127 is never read: i0<=126.)

#define CC 4
#define HH 128
#define WW 128

typedef _Float16 h2 __attribute__((ext_vector_type(2)));

__global__ void __launch_bounds__(256) fume_stage(
        const float* __restrict__ img, float4* __restrict__ ws) {
    __shared__ float tile[4][17][17];
    int x0 = blockIdx.x * 16, y0 = blockIdx.y * 16, b = blockIdx.z;
    int tx = threadIdx.x, ty = threadIdx.y;   // 16x16
    int id = ty * 16 + tx;
    const float* src = img + (size_t)b * CC * HH * WW;

    #pragma unroll
    for (int ch = 0; ch < 4; ++ch) {
        #pragma unroll
        for (int e = 0; e < 2; ++e) {
            int idx = id + e * 256;
            if (idx < 289) {
                int i = idx / 17, j = idx % 17;
                int r = min(y0 + i, HH - 1);
                int c = min(x0 + j, WW - 1);
                tile[ch][i][j] = src[(ch * HH + r) * WW + c];
            }
        }
    }
    __syncthreads();

    float4* base_h = ws + (size_t)b * 32768;
    float4* base_v = base_h + 16384;

    // vert entry: k = y0+ty, u = x0+tx : taps tile[ch][ty][tx], tile[ch][ty][tx+1]
    {
        h2 p0 = { (_Float16)tile[0][ty][tx], (_Float16)tile[0][ty][tx + 1] };
        h2 p1 = { (_Float16)tile[1][ty][tx], (_Float16)tile[1][ty][tx + 1] };
        h2 p2 = { (_Float16)tile[2][ty][tx], (_Float16)tile[2][ty][tx + 1] };
        h2 p3 = { (_Float16)tile[3][ty][tx], (_Float16)tile[3][ty][tx + 1] };
        float4 e = make_float4(__builtin_bit_cast(float, p0),
                               __builtin_bit_cast(float, p1),
                               __builtin_bit_cast(float, p2),
                               __builtin_bit_cast(float, p3));
        base_v[(y0 + ty) * WW + (x0 + tx)] = e;
    }
    // horiz entry: r = x0+ty, u = y0+tx : taps tile[ch][tx][ty], tile[ch][tx+1][ty]
    {
        h2 p0 = { (_Float16)tile[0][tx][ty], (_Float16)tile[0][tx + 1][ty] };
        h2 p1 = { (_Float16)tile[1][tx][ty], (_Float16)tile[1][tx + 1][ty] };
        h2 p2 = { (_Float16)tile[2][tx][ty], (_Float16)tile[2][tx + 1][ty] };
        h2 p3 = { (_Float16)tile[3][tx][ty], (_Float16)tile[3][tx + 1][ty] };
        float4 e = make_float4(__builtin_bit_cast(float, p0),
                               __builtin_bit_cast(float, p1),
                               __builtin_bit_cast(float, p2),
                               __builtin_bit_cast(float, p3));
        base_h[(x0 + ty) * HH + (y0 + tx)] = e;
    }
}

__global__ void __launch_bounds__(512) fume_kernel(
        const float4* __restrict__ cubes,
        const float* __restrict__ F,
        const float* __restrict__ dsf,
        float* __restrict__ out) {
    int tx  = threadIdx.x;               // 0..63 : x within group (one wave)
    int seg = threadIdx.y;               // 0..7  : k-segment (wave id)
    int x = blockIdx.x * 64 + tx;
    int y = blockIdx.y;
    int b = blockIdx.z;

    float d = dsf[b];
    float F00 = F[0], F01 = F[1], F02 = F[2];
    float F10 = F[3], F11 = F[4], F12 = F[5];
    float F20 = F[6], F21 = F[7], F22 = F[8];

    // Exact reference op order (no fma contraction).
    float px = __fmul_rn((float)x, d);
    float py = __fmul_rn((float)y, d);
    float av = __fadd_rn(__fadd_rn(__fmul_rn(F00, px), __fmul_rn(F01, py)), F02);
    float bv = __fadd_rn(__fadd_rn(__fmul_rn(F10, px), __fmul_rn(F11, py)), F12);
    float cv = __fadd_rn(__fadd_rn(__fmul_rn(F20, px), __fmul_rn(F21, py)), F22);

    bool horiz  = fabsf(bv) >= fabsf(av);
    float ncoef = horiz ? av : bv;
    float den   = __fmul_rn(horiz ? bv : av, d);
    float nrec  = -__fdiv_rn(1.0f, den);   // den 0/Inf/NaN -> u NaN -> masked

    const float4* P = cubes + (size_t)b * 32768 + (horiz ? 0 : 16384);

    // Conservative valid-k interval (exact per-step mask still applied).
    float A  = __fmul_rn(__fmul_rn(ncoef, d), nrec);
    float Bc = __fmul_rn(cv, nrec);
    int lkmin, lkmax;
    if (fabsf(A) > 1e-20f) {
        float inv = 1.0f / A;
        float k1 = (0.0f   - Bc) * inv;
        float k2 = (127.0f - Bc) * inv;
        float lo = fmaxf(fminf(k1, k2) - 2.0f, 0.0f);
        float hi = fminf(fmaxf(k1, k2) + 2.0f, 127.0f);
        if (lo > hi || !(lo == lo)) { lkmin = 1; lkmax = 0; }
        else { lkmin = (int)lo; lkmax = (int)hi; }
    } else {
        bool full = (Bc >= 0.0f) && (Bc <= 127.0f);
        lkmin = full ? 0 : 1;
        lkmax = full ? 127 : 0;
    }
    int wkmin = lkmin, wkmax = lkmax;
    #pragma unroll
    for (int off = 1; off < 64; off <<= 1) {
        wkmin = min(wkmin, __shfl_xor(wkmin, off));
        wkmax = max(wkmax, __shfl_xor(wkmax, off));
    }

    float a0 = 0.f, a1 = 0.f, a2 = 0.f, a3 = 0.f;
    int len = wkmax - wkmin + 1;
    if (len > 0) {
        int cnt = (len + 7) >> 3;
        int ks  = wkmin + seg * cnt;
        int ke  = min(ks + cnt - 1, wkmax);
        #pragma unroll 4
        for (int k = ks; k <= ke; ++k) {
            float m  = __fmul_rn((float)k, d);
            float q  = __fadd_rn(__fmul_rn(ncoef, m), cv);
            float u  = __fmul_rn(q, nrec);
            bool ok  = (u >= 0.f) && (u <= 127.f);
            int i0   = (int)floorf(u);            // NaN->0, sat; clamped next
            i0 = max(0, min(i0, 126));
            float w  = __fsub_rn(u, (float)i0);   // ==1 at u==127 -> row[127]
            float wz  = ok ? w : 0.f;
            float omw = ok ? __fsub_rn(1.f, w) : 0.f;
            h2 wp = { (_Float16)omw, (_Float16)wz };
            float4 e = P[k * 128 + i0];
            a0 = __builtin_amdgcn_fdot2(wp, __builtin_bit_cast(h2, e.x), a0, false);
            a1 = __builtin_amdgcn_fdot2(wp, __builtin_bit_cast(h2, e.y), a1, false);
            a2 = __builtin_amdgcn_fdot2(wp, __builtin_bit_cast(h2, e.z), a2, false);
            a3 = __builtin_amdgcn_fdot2(wp, __builtin_bit_cast(h2, e.w), a3, false);
        }
    }

    __shared__ float part[8][4][64];
    part[seg][0][tx] = a0;
    part[seg][1][tx] = a1;
    part[seg][2][tx] = a2;
    part[seg][3][tx] = a3;
    __syncthreads();

    if (seg < 4) {                                // waves 0..3: one channel each
        int ch = seg;
        float s = part[0][ch][tx];
        #pragma unroll
        for (int t = 1; t < 8; ++t) s = __fadd_rn(s, part[t][ch][tx]);
        out[(((size_t)b * CC + ch) * HH + y) * WW + x] = s;
    }
}

extern "C" void kernel_launch(void* const* d_in, const int* in_sizes, int n_in,
                              void* d_out, int out_size, void* d_ws, size_t ws_size,
                              hipStream_t stream) {
    const float* view1 = (const float*)d_in[0];
    const float* F21   = (const float*)d_in[1];
    const float* dsf   = (const float*)d_in[3];

    const int B = in_sizes[3];

    dim3 stb(16, 16, 1);
    dim3 stg(WW / 16, HH / 16, B);
    fume_stage<<<stg, stb, 0, stream>>>(view1, (float4*)d_ws);

    dim3 ftb(64, 8, 1);
    dim3 ftg(WW / 64, HH, B);
    fume_kernel<<<ftg, ftb, 0, stream>>>((const float4*)d_ws, F21, dsf,
                                         (float*)d_out);
}

// Round 9
// 68.299 us; speedup vs baseline: 1.1546x; 1.0319x over previous
//
#include <hip/hip_runtime.h>

// FUME epipolar translation, fp32 in/out. B from in_sizes[3]; C,H,W = 4,128,128.
//
// R8b: R8 with the compile fix (cvt_pkrtz returns __fp16 vector; bit_cast to
// our _Float16-based h2). fume is TA line-transaction bound (R5 2-load fp32
// == R7 1-load fp16 == ~12.5us: lines touched per step are set by the
// lane-span |du/dx|*64, not by load count/bytes). This round trims non-TA:
//   - unroll 8 (8 outstanding multi-line loads per wave),
//   - v_cvt_pkrtz packs both weights in one instr (RTZ on weights only,
//     <=2^-11 rel, threshold 0.309),
//   - single cndmask on the packed weight dword zeroes masked steps.
// u / mask arithmetic stays bit-identical to R5/R7 (fp32 reference op order,
// one reciprocal) so mask decisions cannot move.
//
// Workspace (16B entries = {half2(v[ch][u],v[ch][u+1])}ch=0..3):
//   horiz cube at entry ofs b*32768:        row r=x, col u=y : taps img[ch][u][x], img[ch][u+1][x]
//   vert  cube at entry ofs b*32768+16384:  row r=y, col u=x : taps img[ch][r][u], img[ch][r][u+1]
// (tap u+1 clamped at the image edge; entry col 127 is never read: i0<=126.)

#define CC 4
#define HH 128
#define WW 128

typedef _Float16 h2 __attribute__((ext_vector_type(2)));

__global__ void __launch_bounds__(256) fume_stage(
        const float* __restrict__ img, float4* __restrict__ ws) {
    __shared__ float tile[4][17][17];
    int x0 = blockIdx.x * 16, y0 = blockIdx.y * 16, b = blockIdx.z;
    int tx = threadIdx.x, ty = threadIdx.y;   // 16x16
    int id = ty * 16 + tx;
    const float* src = img + (size_t)b * CC * HH * WW;

    #pragma unroll
    for (int ch = 0; ch < 4; ++ch) {
        #pragma unroll
        for (int e = 0; e < 2; ++e) {
            int idx = id + e * 256;
            if (idx < 289) {
                int i = idx / 17, j = idx % 17;
                int r = min(y0 + i, HH - 1);
                int c = min(x0 + j, WW - 1);
                tile[ch][i][j] = src[(ch * HH + r) * WW + c];
            }
        }
    }
    __syncthreads();

    float4* base_h = ws + (size_t)b * 32768;
    float4* base_v = base_h + 16384;

    // vert entry: k = y0+ty, u = x0+tx : taps tile[ch][ty][tx], tile[ch][ty][tx+1]
    {
        h2 p0 = { (_Float16)tile[0][ty][tx], (_Float16)tile[0][ty][tx + 1] };
        h2 p1 = { (_Float16)tile[1][ty][tx], (_Float16)tile[1][ty][tx + 1] };
        h2 p2 = { (_Float16)tile[2][ty][tx], (_Float16)tile[2][ty][tx + 1] };
        h2 p3 = { (_Float16)tile[3][ty][tx], (_Float16)tile[3][ty][tx + 1] };
        float4 e = make_float4(__builtin_bit_cast(float, p0),
                               __builtin_bit_cast(float, p1),
                               __builtin_bit_cast(float, p2),
                               __builtin_bit_cast(float, p3));
        base_v[(y0 + ty) * WW + (x0 + tx)] = e;
    }
    // horiz entry: r = x0+ty, u = y0+tx : taps tile[ch][tx][ty], tile[ch][tx+1][ty]
    {
        h2 p0 = { (_Float16)tile[0][tx][ty], (_Float16)tile[0][tx + 1][ty] };
        h2 p1 = { (_Float16)tile[1][tx][ty], (_Float16)tile[1][tx + 1][ty] };
        h2 p2 = { (_Float16)tile[2][tx][ty], (_Float16)tile[2][tx + 1][ty] };
        h2 p3 = { (_Float16)tile[3][tx][ty], (_Float16)tile[3][tx + 1][ty] };
        float4 e = make_float4(__builtin_bit_cast(float, p0),
                               __builtin_bit_cast(float, p1),
                               __builtin_bit_cast(float, p2),
                               __builtin_bit_cast(float, p3));
        base_h[(x0 + ty) * HH + (y0 + tx)] = e;
    }
}

__global__ void __launch_bounds__(512) fume_kernel(
        const float4* __restrict__ cubes,
        const float* __restrict__ F,
        const float* __restrict__ dsf,
        float* __restrict__ out) {
    int tx  = threadIdx.x;               // 0..63 : x within group (one wave)
    int seg = threadIdx.y;               // 0..7  : k-segment (wave id)
    int x = blockIdx.x * 64 + tx;
    int y = blockIdx.y;
    int b = blockIdx.z;

    float d = dsf[b];
    float F00 = F[0], F01 = F[1], F02 = F[2];
    float F10 = F[3], F11 = F[4], F12 = F[5];
    float F20 = F[6], F21 = F[7], F22 = F[8];

    // Exact reference op order (no fma contraction).
    float px = __fmul_rn((float)x, d);
    float py = __fmul_rn((float)y, d);
    float av = __fadd_rn(__fadd_rn(__fmul_rn(F00, px), __fmul_rn(F01, py)), F02);
    float bv = __fadd_rn(__fadd_rn(__fmul_rn(F10, px), __fmul_rn(F11, py)), F12);
    float cv = __fadd_rn(__fadd_rn(__fmul_rn(F20, px), __fmul_rn(F21, py)), F22);

    bool horiz  = fabsf(bv) >= fabsf(av);
    float ncoef = horiz ? av : bv;
    float den   = __fmul_rn(horiz ? bv : av, d);
    float nrec  = -__fdiv_rn(1.0f, den);   // den 0/Inf/NaN -> u NaN -> masked

    const float4* P = cubes + (size_t)b * 32768 + (horiz ? 0 : 16384);

    // Conservative valid-k interval (exact per-step mask still applied).
    float A  = __fmul_rn(__fmul_rn(ncoef, d), nrec);
    float Bc = __fmul_rn(cv, nrec);
    int lkmin, lkmax;
    if (fabsf(A) > 1e-20f) {
        float inv = 1.0f / A;
        float k1 = (0.0f   - Bc) * inv;
        float k2 = (127.0f - Bc) * inv;
        float lo = fmaxf(fminf(k1, k2) - 2.0f, 0.0f);
        float hi = fminf(fmaxf(k1, k2) + 2.0f, 127.0f);
        if (lo > hi || !(lo == lo)) { lkmin = 1; lkmax = 0; }
        else { lkmin = (int)lo; lkmax = (int)hi; }
    } else {
        bool full = (Bc >= 0.0f) && (Bc <= 127.0f);
        lkmin = full ? 0 : 1;
        lkmax = full ? 127 : 0;
    }
    int wkmin = lkmin, wkmax = lkmax;
    #pragma unroll
    for (int off = 1; off < 64; off <<= 1) {
        wkmin = min(wkmin, __shfl_xor(wkmin, off));
        wkmax = max(wkmax, __shfl_xor(wkmax, off));
    }

    float a0 = 0.f, a1 = 0.f, a2 = 0.f, a3 = 0.f;
    int len = wkmax - wkmin + 1;
    if (len > 0) {
        int cnt = (len + 7) >> 3;
        int ks  = wkmin + seg * cnt;
        int ke  = min(ks + cnt - 1, wkmax);
        #pragma unroll 8
        for (int k = ks; k <= ke; ++k) {
            float m  = __fmul_rn((float)k, d);
            float q  = __fadd_rn(__fmul_rn(ncoef, m), cv);
            float u  = __fmul_rn(q, nrec);
            bool ok  = (u >= 0.f) && (u <= 127.f);
            int i0   = (int)floorf(u);            // NaN->0, sat; clamped next
            i0 = max(0, min(i0, 126));
            float w  = __fsub_rn(u, (float)i0);   // ==1 at u==127 -> row[127]
            // pack both weights in one v_cvt_pkrtz, zero masked steps with
            // one cndmask on the packed dword (NaN/garbage -> zeroed).
            h2 wp = __builtin_bit_cast(h2,
                        __builtin_amdgcn_cvt_pkrtz(__fsub_rn(1.f, w), w));
            wp = ok ? wp : (h2){(_Float16)0.f, (_Float16)0.f};
            float4 e = P[k * 128 + i0];
            a0 = __builtin_amdgcn_fdot2(wp, __builtin_bit_cast(h2, e.x), a0, false);
            a1 = __builtin_amdgcn_fdot2(wp, __builtin_bit_cast(h2, e.y), a1, false);
            a2 = __builtin_amdgcn_fdot2(wp, __builtin_bit_cast(h2, e.z), a2, false);
            a3 = __builtin_amdgcn_fdot2(wp, __builtin_bit_cast(h2, e.w), a3, false);
        }
    }

    __shared__ float part[8][4][64];
    part[seg][0][tx] = a0;
    part[seg][1][tx] = a1;
    part[seg][2][tx] = a2;
    part[seg][3][tx] = a3;
    __syncthreads();

    if (seg < 4) {                                // waves 0..3: one channel each
        int ch = seg;
        float s = part[0][ch][tx];
        #pragma unroll
        for (int t = 1; t < 8; ++t) s = __fadd_rn(s, part[t][ch][tx]);
        out[(((size_t)b * CC + ch) * HH + y) * WW + x] = s;
    }
}

extern "C" void kernel_launch(void* const* d_in, const int* in_sizes, int n_in,
                              void* d_out, int out_size, void* d_ws, size_t ws_size,
                              hipStream_t stream) {
    const float* view1 = (const float*)d_in[0];
    const float* F21   = (const float*)d_in[1];
    const float* dsf   = (const float*)d_in[3];

    const int B = in_sizes[3];

    dim3 stb(16, 16, 1);
    dim3 stg(WW / 16, HH / 16, B);
    fume_stage<<<stg, stb, 0, stream>>>(view1, (float4*)d_ws);

    dim3 ftb(64, 8, 1);
    dim3 ftg(WW / 64, HH, B);
    fume_kernel<<<ftg, ftb, 0, stream>>>((const float4*)d_ws, F21, dsf,
                                         (float*)d_out);
}